// Round 1
// baseline (443.575 us; speedup 1.0000x reference)
//
#include <hip/hip_runtime.h>

// INT8 LSTM cell, fused single-GEMM formulation:
//   A = [x | h_prev]  (M=16384, K=1024)
//   W = [w_ih | w_hh] (N=2048 rows, K=1024)   gates = A @ W^T + (b_ih + b_hh)
// Block tile: 128 rows x 32 gate-cols (= 128x128 effective MFMA tile across 4 gates).
// Each wave: 32 rows x {2 col-frags x 4 gates} -> i/f/g/o for a given (row,col) are
// in the SAME lane -> epilogue is in-register, no gates materialization.

typedef __attribute__((ext_vector_type(8))) short short8;  // 8 bf16 in 4 VGPRs
typedef __attribute__((ext_vector_type(4))) float f32x4;

#define BATCH 16384
#define HID 512
#define KTOT 1024
#define BM 128
#define BK 64
#define LDSK 72  // 64 + 8 pad -> 144B row stride, 2-way bank alias (free)

__device__ __forceinline__ unsigned short f2bf(float f) {
    unsigned u = __builtin_bit_cast(unsigned, f);
    u += 0x7FFFu + ((u >> 16) & 1u);  // round-to-nearest-even
    return (unsigned short)(u >> 16);
}

__device__ __forceinline__ float sigmoidf_(float v) { return 1.0f / (1.0f + __expf(-v)); }
__device__ __forceinline__ float tanhf_(float v) { return 1.0f - 2.0f / (__expf(2.0f * v) + 1.0f); }

__global__ __launch_bounds__(256, 3) void lstm_fused(
    const float* __restrict__ x, const float* __restrict__ h_prev,
    const float* __restrict__ c_prev, const float* __restrict__ w_ih,
    const float* __restrict__ w_hh, const float* __restrict__ b_ih,
    const float* __restrict__ b_hh, float* __restrict__ h_out,
    float* __restrict__ c_out)
{
    __shared__ unsigned short sA[BM][LDSK];  // 18 KB
    __shared__ unsigned short sW[BM][LDSK];  // 18 KB  (rows: [Wi(32)|Wf(32)|Wg(32)|Wo(32)])

    const int t = threadIdx.x;
    const int bn = blockIdx.x & 15;   // 16 n-blocks of 32 gate-cols
    const int bm = blockIdx.x >> 4;   // 128 m-blocks; consecutive bids share A panel (L2)
    const int n0 = bn * 32;
    const int rowBase = bm * BM;

    // staging thread map: 16 rows x 16 float4-cols per pass, 8 passes
    const int srow = t >> 4;   // 0..15
    const int scol = t & 15;   // 0..15

    const int lane = t & 63;
    const int wv = t >> 6;          // wave 0..3 -> rows [wv*32, wv*32+32)
    const int colin = lane & 15;
    const int quad = lane >> 4;

    f32x4 acc[2][2][4];  // [row-frag][col-frag][gate]
    #pragma unroll
    for (int rf = 0; rf < 2; ++rf)
        #pragma unroll
        for (int cc = 0; cc < 2; ++cc)
            #pragma unroll
            for (int g = 0; g < 4; ++g)
                acc[rf][cc][g] = (f32x4){0.f, 0.f, 0.f, 0.f};

    for (int k0 = 0; k0 < KTOT; k0 += BK) {
        const int kk = (k0 < 512) ? k0 : (k0 - 512);
        const float* aSrc = (k0 < 512) ? x : h_prev;
        const float* wSrc = (k0 < 512) ? w_ih : w_hh;

        __syncthreads();
        #pragma unroll
        for (int p = 0; p < 8; ++p) {
            const int r = srow + p * 16;
            // A tile: row (rowBase+r), k cols [kk + scol*4, +4)
            const float4 av = *(const float4*)(aSrc + (size_t)(rowBase + r) * 512 + kk + scol * 4);
            ushort4 ap;
            ap.x = f2bf(av.x); ap.y = f2bf(av.y); ap.z = f2bf(av.z); ap.w = f2bf(av.w);
            *(ushort4*)&sA[r][scol * 4] = ap;
            // W tile: lds row r -> gate r/32, weight row gate*512 + n0 + (r%32)
            const int gate = r >> 5;
            const int rr = r & 31;
            const float4 wvv = *(const float4*)(wSrc + (size_t)(gate * 512 + n0 + rr) * 512 + kk + scol * 4);
            ushort4 wp;
            wp.x = f2bf(wvv.x); wp.y = f2bf(wvv.y); wp.z = f2bf(wvv.z); wp.w = f2bf(wvv.w);
            *(ushort4*)&sW[r][scol * 4] = wp;
        }
        __syncthreads();

        #pragma unroll
        for (int ks = 0; ks < 2; ++ks) {
            short8 af[2];
            #pragma unroll
            for (int rf = 0; rf < 2; ++rf)
                af[rf] = *(const short8*)&sA[wv * 32 + rf * 16 + colin][ks * 32 + quad * 8];
            short8 bfr[2][4];
            #pragma unroll
            for (int cc = 0; cc < 2; ++cc)
                #pragma unroll
                for (int g = 0; g < 4; ++g)
                    bfr[cc][g] = *(const short8*)&sW[g * 32 + cc * 16 + colin][ks * 32 + quad * 8];
            #pragma unroll
            for (int rf = 0; rf < 2; ++rf)
                #pragma unroll
                for (int cc = 0; cc < 2; ++cc)
                    #pragma unroll
                    for (int g = 0; g < 4; ++g)
                        acc[rf][cc][g] = __builtin_amdgcn_mfma_f32_16x16x32_bf16(
                            af[rf], bfr[cc][g], acc[rf][cc][g], 0, 0, 0);
        }
    }

    // Epilogue: all 4 gates for (row,col) live in this lane's accumulators.
    float bsum[2][4];
    #pragma unroll
    for (int cc = 0; cc < 2; ++cc) {
        const int colg = n0 + cc * 16 + colin;
        #pragma unroll
        for (int g = 0; g < 4; ++g)
            bsum[cc][g] = b_ih[g * 512 + colg] + b_hh[g * 512 + colg];
    }

    #pragma unroll
    for (int rf = 0; rf < 2; ++rf) {
        #pragma unroll
        for (int cc = 0; cc < 2; ++cc) {
            const int colg = n0 + cc * 16 + colin;
            #pragma unroll
            for (int reg = 0; reg < 4; ++reg) {
                const int row = rowBase + wv * 32 + rf * 16 + quad * 4 + reg;
                const size_t off = (size_t)row * 512 + colg;
                const float ig = acc[rf][cc][0][reg] + bsum[cc][0];
                const float fg = acc[rf][cc][1][reg] + bsum[cc][1];
                const float gg = acc[rf][cc][2][reg] + bsum[cc][2];
                const float og = acc[rf][cc][3][reg] + bsum[cc][3];
                const float cp = c_prev[off];
                const float cn = sigmoidf_(fg) * cp + sigmoidf_(ig) * tanhf_(gg);
                const float hn = sigmoidf_(og) * tanhf_(cn);
                h_out[off] = hn;
                c_out[off] = cn;
            }
        }
    }
}

extern "C" void kernel_launch(void* const* d_in, const int* in_sizes, int n_in,
                              void* d_out, int out_size, void* d_ws, size_t ws_size,
                              hipStream_t stream) {
    const float* x      = (const float*)d_in[0];
    const float* h_prev = (const float*)d_in[1];
    const float* c_prev = (const float*)d_in[2];
    const float* w_ih   = (const float*)d_in[3];
    const float* w_hh   = (const float*)d_in[4];
    const float* b_ih   = (const float*)d_in[5];
    const float* b_hh   = (const float*)d_in[6];
    float* h_out = (float*)d_out;
    float* c_out = h_out + (size_t)BATCH * HID;

    const int grid = (BATCH / BM) * (HID / 32);  // 128 * 16 = 2048 blocks
    lstm_fused<<<grid, 256, 0, stream>>>(x, h_prev, c_prev, w_ih, w_hh, b_ih, b_hh, h_out, c_out);
}

// Round 2
// 241.984 us; speedup vs baseline: 1.8331x; 1.8331x over previous
//
#include <hip/hip_runtime.h>

// INT8 LSTM cell, fused single-GEMM formulation, m97-style global_load_lds pipeline.
//   A = [x | h_prev]  (M=16384, K=1024)
//   W = [w_ih | w_hh] (N=2048 rows, K=1024)   gates = A @ W^T + (b_ih + b_hh)
//
// Stage 1 (convert kernels): repack A and W fp32->bf16 into d_ws as per-(block,kstep)
//   128x64 tiles, XOR-swizzled (chunk' = chunk ^ (row&7), chunk = 16B = 8 bf16) so the
//   GEMM can stage with global_load_lds (wave-uniform+lane*16, no LDS padding) AND get
//   conflict-free ds_read_b128.
// Stage 2 (GEMM): 128 rows x 32 gate-cols per block (= 128x128 MFMA tile across the 4
//   gates); i/f/g/o for a (row,col) land in the same lane -> in-register LSTM epilogue.

typedef __attribute__((ext_vector_type(8))) short short8;  // 8 bf16 in 4 VGPRs
typedef __attribute__((ext_vector_type(4))) float f32x4;
typedef unsigned int u32;
typedef unsigned short u16;

#define BATCH 16384
#define HID 512
#define KTOT 1024
#define BM 128
#define BK 64
#define KSTEPS 16            // KTOT / BK
#define TILE_BYTES 16384     // 128 rows * 64 bf16 * 2B
#define WSA_BYTES (128ull * KSTEPS * TILE_BYTES)   // 32 MB (128 m-blocks)
#define WSW_BYTES (16ull * KSTEPS * TILE_BYTES)    // 4 MB  (16 n-blocks)
#define WS_NEEDED (WSA_BYTES + WSW_BYTES)

__device__ __forceinline__ u16 f2bf(float f) {
    u32 u = __builtin_bit_cast(u32, f);
    u += 0x7FFFu + ((u >> 16) & 1u);  // round-to-nearest-even
    return (u16)(u >> 16);
}

__device__ __forceinline__ float sigmoidf_(float v) { return 1.0f / (1.0f + __expf(-v)); }
__device__ __forceinline__ float tanhf_(float v) { return 1.0f - 2.0f / (__expf(2.0f * v) + 1.0f); }

__device__ __forceinline__ void gload_lds16(const void* g, void* l) {
    __builtin_amdgcn_global_load_lds(
        (const __attribute__((address_space(1))) u32*)g,
        (__attribute__((address_space(3))) u32*)l, 16, 0, 0);
}

// ---- Stage 1a: pack A = [x | h] into swizzled tiles. One 16B chunk per thread. ----
__global__ __launch_bounds__(256) void pack_a(
    const float* __restrict__ x, const float* __restrict__ h_prev, u16* __restrict__ wsA)
{
    const u32 idx = blockIdx.x * 256 + threadIdx.x;   // chunk index, 2^21 total
    const u32 cphys = idx & 7;
    const u32 row = (idx >> 3) & 127;
    const u32 ks = (idx >> 10) & 15;
    const u32 bm = idx >> 14;
    const u32 clog = cphys ^ (row & 7);
    const u32 m = bm * 128 + row;
    const u32 kglob = ks * 64 + clog * 8;             // multiple of 8, block of 8 k
    const float* src = (kglob < 512) ? (x + (size_t)m * 512 + kglob)
                                     : (h_prev + (size_t)m * 512 + (kglob - 512));
    const float4 v0 = *(const float4*)src;
    const float4 v1 = *(const float4*)(src + 4);
    ushort4 p0, p1;
    p0.x = f2bf(v0.x); p0.y = f2bf(v0.y); p0.z = f2bf(v0.z); p0.w = f2bf(v0.w);
    p1.x = f2bf(v1.x); p1.y = f2bf(v1.y); p1.z = f2bf(v1.z); p1.w = f2bf(v1.w);
    *(ushort4*)(wsA + (size_t)idx * 8) = p0;          // linear chunk order == tile layout
    *(ushort4*)(wsA + (size_t)idx * 8 + 4) = p1;
}

// ---- Stage 1b: pack W = [w_ih | w_hh] with 4-gate interleave into swizzled tiles. ----
__global__ __launch_bounds__(256) void pack_w(
    const float* __restrict__ w_ih, const float* __restrict__ w_hh, u16* __restrict__ wsW)
{
    const u32 idx = blockIdx.x * 256 + threadIdx.x;   // 2^18 total
    const u32 cphys = idx & 7;
    const u32 row = (idx >> 3) & 127;                 // g*32 + rr
    const u32 ks = (idx >> 10) & 15;
    const u32 bn = idx >> 14;
    const u32 clog = cphys ^ (row & 7);
    const u32 g = row >> 5, rr = row & 31;
    const u32 wrow = g * 512 + bn * 32 + rr;
    const u32 kglob = ks * 64 + clog * 8;
    const float* src = (kglob < 512) ? (w_ih + (size_t)wrow * 512 + kglob)
                                     : (w_hh + (size_t)wrow * 512 + (kglob - 512));
    const float4 v0 = *(const float4*)src;
    const float4 v1 = *(const float4*)(src + 4);
    ushort4 p0, p1;
    p0.x = f2bf(v0.x); p0.y = f2bf(v0.y); p0.z = f2bf(v0.z); p0.w = f2bf(v0.w);
    p1.x = f2bf(v1.x); p1.y = f2bf(v1.y); p1.z = f2bf(v1.z); p1.w = f2bf(v1.w);
    *(ushort4*)(wsW + (size_t)idx * 8) = p0;
    *(ushort4*)(wsW + (size_t)idx * 8 + 4) = p1;
}

// ---- Stage 2: GEMM + fused LSTM epilogue. ----
__global__ __launch_bounds__(256, 4) void lstm_gemm(
    const u16* __restrict__ wsA, const u16* __restrict__ wsW,
    const float* __restrict__ c_prev,
    const float* __restrict__ b_ih, const float* __restrict__ b_hh,
    float* __restrict__ h_out, float* __restrict__ c_out)
{
    __shared__ u16 sA[BM * BK];  // 16 KB, swizzled layout, NO padding (global_load_lds)
    __shared__ u16 sW[BM * BK];  // 16 KB

    const int t = threadIdx.x;
    const int bn = blockIdx.x & 15;   // 16 n-blocks of 32 gate-cols
    const int bm = blockIdx.x >> 4;   // consecutive bids share the A panel (L2)
    const int n0 = bn * 32;
    const int rowBase = bm * BM;

    const int lane = t & 63;
    const int wv = t >> 6;
    const int colin = lane & 15;
    const int quad = lane >> 4;
    const int stageOff = wv * 1024 + lane * 16;  // bytes; 4 issues of +4096

    f32x4 acc[2][2][4];  // [row-frag][col-frag][gate]
    #pragma unroll
    for (int rf = 0; rf < 2; ++rf)
        #pragma unroll
        for (int cc = 0; cc < 2; ++cc)
            #pragma unroll
            for (int g = 0; g < 4; ++g)
                acc[rf][cc][g] = (f32x4){0.f, 0.f, 0.f, 0.f};

    const char* gA = (const char*)wsA + (size_t)bm * KSTEPS * TILE_BYTES;
    const char* gW = (const char*)wsW + (size_t)bn * KSTEPS * TILE_BYTES;

    for (int ks = 0; ks < KSTEPS; ++ks) {
        __syncthreads();  // previous compute done before overwrite
        #pragma unroll
        for (int j = 0; j < 4; ++j) {
            const int off = j * 4096 + stageOff;
            gload_lds16(gA + (size_t)ks * TILE_BYTES + off, (char*)sA + off);
            gload_lds16(gW + (size_t)ks * TILE_BYTES + off, (char*)sW + off);
        }
        __syncthreads();  // compiler emits vmcnt(0) drain before barrier

        #pragma unroll
        for (int ks2 = 0; ks2 < 2; ++ks2) {
            short8 af[2];
            #pragma unroll
            for (int rf = 0; rf < 2; ++rf) {
                const int row = wv * 32 + rf * 16 + colin;
                const int boff = row * 128 + (((ks2 * 4 + quad) ^ (row & 7)) * 16);
                af[rf] = *(const short8*)((const char*)sA + boff);
            }
            short8 bfr[2][4];
            #pragma unroll
            for (int cc = 0; cc < 2; ++cc)
                #pragma unroll
                for (int g = 0; g < 4; ++g) {
                    const int row = g * 32 + cc * 16 + colin;
                    const int boff = row * 128 + (((ks2 * 4 + quad) ^ (row & 7)) * 16);
                    bfr[cc][g] = *(const short8*)((const char*)sW + boff);
                }
            #pragma unroll
            for (int rf = 0; rf < 2; ++rf)
                #pragma unroll
                for (int cc = 0; cc < 2; ++cc)
                    #pragma unroll
                    for (int g = 0; g < 4; ++g)
                        acc[rf][cc][g] = __builtin_amdgcn_mfma_f32_16x16x32_bf16(
                            af[rf], bfr[cc][g], acc[rf][cc][g], 0, 0, 0);
        }
    }

    // Epilogue: all 4 gates for (row,col) live in this lane's accumulators.
    float bsum[2][4];
    #pragma unroll
    for (int cc = 0; cc < 2; ++cc) {
        const int colg = n0 + cc * 16 + colin;
        #pragma unroll
        for (int g = 0; g < 4; ++g)
            bsum[cc][g] = b_ih[g * 512 + colg] + b_hh[g * 512 + colg];
    }

    #pragma unroll
    for (int rf = 0; rf < 2; ++rf)
        #pragma unroll
        for (int cc = 0; cc < 2; ++cc) {
            const int colg = n0 + cc * 16 + colin;
            #pragma unroll
            for (int reg = 0; reg < 4; ++reg) {
                const int row = rowBase + wv * 32 + rf * 16 + quad * 4 + reg;
                const size_t off = (size_t)row * 512 + colg;
                const float ig = acc[rf][cc][0][reg] + bsum[cc][0];
                const float fg = acc[rf][cc][1][reg] + bsum[cc][1];
                const float gg = acc[rf][cc][2][reg] + bsum[cc][2];
                const float og = acc[rf][cc][3][reg] + bsum[cc][3];
                const float cp = c_prev[off];
                const float cn = sigmoidf_(fg) * cp + sigmoidf_(ig) * tanhf_(gg);
                const float hn = sigmoidf_(og) * tanhf_(cn);
                h_out[off] = hn;
                c_out[off] = cn;
            }
        }
}

// ---- Fallback (round-1 kernel, proven): used only if ws_size < WS_NEEDED ----
#define LDSK 72
__global__ __launch_bounds__(256, 3) void lstm_fused_v1(
    const float* __restrict__ x, const float* __restrict__ h_prev,
    const float* __restrict__ c_prev, const float* __restrict__ w_ih,
    const float* __restrict__ w_hh, const float* __restrict__ b_ih,
    const float* __restrict__ b_hh, float* __restrict__ h_out,
    float* __restrict__ c_out)
{
    __shared__ u16 sA[BM][LDSK];
    __shared__ u16 sW[BM][LDSK];
    const int t = threadIdx.x;
    const int bn = blockIdx.x & 15, bm = blockIdx.x >> 4;
    const int n0 = bn * 32, rowBase = bm * BM;
    const int srow = t >> 4, scol = t & 15;
    const int lane = t & 63, wv = t >> 6, colin = lane & 15, quad = lane >> 4;
    f32x4 acc[2][2][4];
    #pragma unroll
    for (int rf = 0; rf < 2; ++rf)
        #pragma unroll
        for (int cc = 0; cc < 2; ++cc)
            #pragma unroll
            for (int g = 0; g < 4; ++g) acc[rf][cc][g] = (f32x4){0.f, 0.f, 0.f, 0.f};
    for (int k0 = 0; k0 < KTOT; k0 += BK) {
        const int kk = (k0 < 512) ? k0 : (k0 - 512);
        const float* aSrc = (k0 < 512) ? x : h_prev;
        const float* wSrc = (k0 < 512) ? w_ih : w_hh;
        __syncthreads();
        #pragma unroll
        for (int p = 0; p < 8; ++p) {
            const int r = srow + p * 16;
            const float4 av = *(const float4*)(aSrc + (size_t)(rowBase + r) * 512 + kk + scol * 4);
            ushort4 ap; ap.x = f2bf(av.x); ap.y = f2bf(av.y); ap.z = f2bf(av.z); ap.w = f2bf(av.w);
            *(ushort4*)&sA[r][scol * 4] = ap;
            const int gate = r >> 5, rr = r & 31;
            const float4 wvv = *(const float4*)(wSrc + (size_t)(gate * 512 + n0 + rr) * 512 + kk + scol * 4);
            ushort4 wp; wp.x = f2bf(wvv.x); wp.y = f2bf(wvv.y); wp.z = f2bf(wvv.z); wp.w = f2bf(wvv.w);
            *(ushort4*)&sW[r][scol * 4] = wp;
        }
        __syncthreads();
        #pragma unroll
        for (int ks = 0; ks < 2; ++ks) {
            short8 af[2];
            #pragma unroll
            for (int rf = 0; rf < 2; ++rf)
                af[rf] = *(const short8*)&sA[wv * 32 + rf * 16 + colin][ks * 32 + quad * 8];
            short8 bfr[2][4];
            #pragma unroll
            for (int cc = 0; cc < 2; ++cc)
                #pragma unroll
                for (int g = 0; g < 4; ++g)
                    bfr[cc][g] = *(const short8*)&sW[g * 32 + cc * 16 + colin][ks * 32 + quad * 8];
            #pragma unroll
            for (int rf = 0; rf < 2; ++rf)
                #pragma unroll
                for (int cc = 0; cc < 2; ++cc)
                    #pragma unroll
                    for (int g = 0; g < 4; ++g)
                        acc[rf][cc][g] = __builtin_amdgcn_mfma_f32_16x16x32_bf16(
                            af[rf], bfr[cc][g], acc[rf][cc][g], 0, 0, 0);
        }
    }
    float bsum[2][4];
    #pragma unroll
    for (int cc = 0; cc < 2; ++cc) {
        const int colg = n0 + cc * 16 + colin;
        #pragma unroll
        for (int g = 0; g < 4; ++g) bsum[cc][g] = b_ih[g * 512 + colg] + b_hh[g * 512 + colg];
    }
    #pragma unroll
    for (int rf = 0; rf < 2; ++rf)
        #pragma unroll
        for (int cc = 0; cc < 2; ++cc) {
            const int colg = n0 + cc * 16 + colin;
            #pragma unroll
            for (int reg = 0; reg < 4; ++reg) {
                const int row = rowBase + wv * 32 + rf * 16 + quad * 4 + reg;
                const size_t off = (size_t)row * 512 + colg;
                const float ig = acc[rf][cc][0][reg] + bsum[cc][0];
                const float fg = acc[rf][cc][1][reg] + bsum[cc][1];
                const float gg = acc[rf][cc][2][reg] + bsum[cc][2];
                const float og = acc[rf][cc][3][reg] + bsum[cc][3];
                const float cp = c_prev[off];
                const float cn = sigmoidf_(fg) * cp + sigmoidf_(ig) * tanhf_(gg);
                const float hn = sigmoidf_(og) * tanhf_(cn);
                h_out[off] = hn;
                c_out[off] = cn;
            }
        }
}

extern "C" void kernel_launch(void* const* d_in, const int* in_sizes, int n_in,
                              void* d_out, int out_size, void* d_ws, size_t ws_size,
                              hipStream_t stream) {
    const float* x      = (const float*)d_in[0];
    const float* h_prev = (const float*)d_in[1];
    const float* c_prev = (const float*)d_in[2];
    const float* w_ih   = (const float*)d_in[3];
    const float* w_hh   = (const float*)d_in[4];
    const float* b_ih   = (const float*)d_in[5];
    const float* b_hh   = (const float*)d_in[6];
    float* h_out = (float*)d_out;
    float* c_out = h_out + (size_t)BATCH * HID;
    const int grid = (BATCH / BM) * (HID / 32);  // 2048 blocks

    if (ws_size >= WS_NEEDED) {
        u16* wsA = (u16*)d_ws;
        u16* wsW = (u16*)((char*)d_ws + WSA_BYTES);
        pack_a<<<(WSA_BYTES / 16) / 256, 256, 0, stream>>>(x, h_prev, wsA);
        pack_w<<<(WSW_BYTES / 16) / 256, 256, 0, stream>>>(w_ih, w_hh, wsW);
        lstm_gemm<<<grid, 256, 0, stream>>>(wsA, wsW, c_prev, b_ih, b_hh, h_out, c_out);
    } else {
        lstm_fused_v1<<<grid, 256, 0, stream>>>(x, h_prev, c_prev, w_ih, w_hh, b_ih, b_hh, h_out, c_out);
    }
}

// Round 3
// 233.678 us; speedup vs baseline: 1.8982x; 1.0355x over previous
//
#include <hip/hip_runtime.h>

// INT8 LSTM cell, fused single-GEMM, m97-style global_load_lds pipeline, v3:
//   A = [x | h_prev]  (M=16384, K=1024),  W = [w_ih | w_hh] (N=2048, K=1024)
//   gates = A @ W^T + (b_ih + b_hh)  -> in-register LSTM epilogue (4 gates/lane).
// v3: wave tile 64x128 (4 row-frags x 2 col-frags x 4 gates), BM=256, BN=32 gate-cols.
//     Per wave-BK: 64 MFMA vs 24 ds_read_b128 (was 32 vs 20) -> LDS-read pressure
//     drops from 1.9:1 to 1.1:1 of MFMA cycles. Packs fused into one kernel.
//     Nontemporal for streamed c_prev/h_out/c_out to keep ws resident in L2/L3.

typedef __attribute__((ext_vector_type(8))) short short8;  // 8 bf16 in 4 VGPRs
typedef __attribute__((ext_vector_type(4))) float f32x4;
typedef unsigned int u32;
typedef unsigned short u16;

#define BATCH 16384
#define HID 512
#define KTOT 1024
#define BM 256
#define BK 64
#define KSTEPS 16                 // KTOT / BK
#define TILEA_BYTES 32768         // 256 rows * 64 bf16 * 2B
#define TILEW_BYTES 16384         // 128 rows * 64 bf16 * 2B
#define NBM 64                    // BATCH / BM
#define NBN 16                    // HID / 32
#define WSA_BYTES ((size_t)NBM * KSTEPS * TILEA_BYTES)   // 32 MB
#define WSW_BYTES ((size_t)NBN * KSTEPS * TILEW_BYTES)   // 4 MB
#define WS_NEEDED (WSA_BYTES + WSW_BYTES)
#define A_CHUNKS (1u << 21)       // 64*16*256*8
#define W_CHUNKS (1u << 18)       // 16*16*128*8

__device__ __forceinline__ u16 f2bf(float f) {
    u32 u = __builtin_bit_cast(u32, f);
    u += 0x7FFFu + ((u >> 16) & 1u);  // RNE
    return (u16)(u >> 16);
}

__device__ __forceinline__ float sigmoidf_(float v) { return 1.0f / (1.0f + __expf(-v)); }
__device__ __forceinline__ float tanhf_(float v) { return 1.0f - 2.0f / (__expf(2.0f * v) + 1.0f); }

__device__ __forceinline__ void gload_lds16(const void* g, void* l) {
    __builtin_amdgcn_global_load_lds(
        (const __attribute__((address_space(1))) u32*)g,
        (__attribute__((address_space(3))) u32*)l, 16, 0, 0);
}

// ---- Stage 1: pack A and W fp32->bf16 into swizzled tiles (one fused kernel). ----
// Tile layout: chunk(16B) index within tile = row*8 + cphys, cphys = clog ^ (row&7).
__global__ __launch_bounds__(256) void pack_all(
    const float* __restrict__ x, const float* __restrict__ h_prev,
    const float* __restrict__ w_ih, const float* __restrict__ w_hh,
    u16* __restrict__ wsA, u16* __restrict__ wsW)
{
    const u32 idx = blockIdx.x * 256 + threadIdx.x;
    const float* src;
    u16* dst;
    if (idx < A_CHUNKS) {
        const u32 cphys = idx & 7;
        const u32 row = (idx >> 3) & 255;
        const u32 ks = (idx >> 11) & 15;
        const u32 bm = idx >> 15;
        const u32 clog = cphys ^ (row & 7);
        const u32 m = bm * 256 + row;
        const u32 kglob = ks * 64 + clog * 8;
        src = (kglob < 512) ? (x + (size_t)m * 512 + kglob)
                            : (h_prev + (size_t)m * 512 + (kglob - 512));
        dst = wsA + (size_t)idx * 8;
    } else {
        const u32 widx = idx - A_CHUNKS;
        const u32 cphys = widx & 7;
        const u32 row = (widx >> 3) & 127;   // g*32 + rr
        const u32 ks = (widx >> 10) & 15;
        const u32 bn = widx >> 14;
        const u32 clog = cphys ^ (row & 7);
        const u32 g = row >> 5, rr = row & 31;
        const u32 wrow = g * 512 + bn * 32 + rr;
        const u32 kglob = ks * 64 + clog * 8;
        src = (kglob < 512) ? (w_ih + (size_t)wrow * 512 + kglob)
                            : (w_hh + (size_t)wrow * 512 + (kglob - 512));
        dst = wsW + (size_t)widx * 8;
    }
    const float4 v0 = *(const float4*)src;
    const float4 v1 = *(const float4*)(src + 4);
    ushort4 p0, p1;
    p0.x = f2bf(v0.x); p0.y = f2bf(v0.y); p0.z = f2bf(v0.z); p0.w = f2bf(v0.w);
    p1.x = f2bf(v1.x); p1.y = f2bf(v1.y); p1.z = f2bf(v1.z); p1.w = f2bf(v1.w);
    *(ushort4*)dst = p0;
    *(ushort4*)(dst + 4) = p1;
}

// ---- Stage 2: GEMM + fused LSTM epilogue. BM=256, 4 waves of 64 rows each. ----
__global__ __launch_bounds__(256, 2) void lstm_gemm(
    const u16* __restrict__ wsA, const u16* __restrict__ wsW,
    const float* __restrict__ c_prev,
    const float* __restrict__ b_ih, const float* __restrict__ b_hh,
    float* __restrict__ h_out, float* __restrict__ c_out)
{
    __shared__ u16 sA[BM * BK];   // 32 KB, swizzled, NO padding (global_load_lds)
    __shared__ u16 sW[128 * BK];  // 16 KB

    const int t = threadIdx.x;
    const int bn = blockIdx.x & 15;   // 16 n-blocks of 32 gate-cols
    const int bm = blockIdx.x >> 4;   // consecutive bids share the A panel (L2)
    const int n0 = bn * 32;
    const int rowBase = bm * BM;

    const int lane = t & 63;
    const int wv = t >> 6;            // wave -> rows [wv*64, wv*64+64)
    const int colin = lane & 15;
    const int quad = lane >> 4;

    f32x4 acc[4][2][4];  // [row-frag][col-frag][gate] = 128 VGPRs
    #pragma unroll
    for (int rf = 0; rf < 4; ++rf)
        #pragma unroll
        for (int cc = 0; cc < 2; ++cc)
            #pragma unroll
            for (int g = 0; g < 4; ++g)
                acc[rf][cc][g] = (f32x4){0.f, 0.f, 0.f, 0.f};

    const char* gA = (const char*)wsA + (size_t)bm * KSTEPS * TILEA_BYTES;
    const char* gW = (const char*)wsW + (size_t)bn * KSTEPS * TILEW_BYTES;
    const int stageOff = t * 16;      // = wv*1024 + lane*16: wave-uniform base + lane*16

    #pragma unroll 1
    for (int ks = 0; ks < KSTEPS; ++ks) {
        __syncthreads();
        #pragma unroll
        for (int j = 0; j < 8; ++j)
            gload_lds16(gA + (size_t)ks * TILEA_BYTES + j * 4096 + stageOff,
                        (char*)sA + j * 4096 + stageOff);
        #pragma unroll
        for (int j = 0; j < 4; ++j)
            gload_lds16(gW + (size_t)ks * TILEW_BYTES + j * 4096 + stageOff,
                        (char*)sW + j * 4096 + stageOff);
        __syncthreads();

        #pragma unroll
        for (int ks2 = 0; ks2 < 2; ++ks2) {
            short8 af[4];
            #pragma unroll
            for (int rf = 0; rf < 4; ++rf) {
                const int row = wv * 64 + rf * 16 + colin;
                const int boff = row * 128 + (((ks2 * 4 + quad) ^ (row & 7)) * 16);
                af[rf] = *(const short8*)((const char*)sA + boff);
            }
            short8 bfr[2][4];
            #pragma unroll
            for (int cc = 0; cc < 2; ++cc)
                #pragma unroll
                for (int g = 0; g < 4; ++g) {
                    const int wrow = g * 32 + cc * 16 + colin;
                    const int boff = wrow * 128 + (((ks2 * 4 + quad) ^ (wrow & 7)) * 16);
                    bfr[cc][g] = *(const short8*)((const char*)sW + boff);
                }
            #pragma unroll
            for (int rf = 0; rf < 4; ++rf)
                #pragma unroll
                for (int cc = 0; cc < 2; ++cc)
                    #pragma unroll
                    for (int g = 0; g < 4; ++g)
                        acc[rf][cc][g] = __builtin_amdgcn_mfma_f32_16x16x32_bf16(
                            af[rf], bfr[cc][g], acc[rf][cc][g], 0, 0, 0);
        }
    }

    // Epilogue: i/f/g/o for each (row,col) are in this lane's accumulators.
    float bsum[2][4];
    #pragma unroll
    for (int cc = 0; cc < 2; ++cc) {
        const int colg = n0 + cc * 16 + colin;
        #pragma unroll
        for (int g = 0; g < 4; ++g)
            bsum[cc][g] = b_ih[g * 512 + colg] + b_hh[g * 512 + colg];
    }

    #pragma unroll
    for (int rf = 0; rf < 4; ++rf)
        #pragma unroll
        for (int cc = 0; cc < 2; ++cc) {
            const int colg = n0 + cc * 16 + colin;
            #pragma unroll
            for (int reg = 0; reg < 4; ++reg) {
                const int row = rowBase + wv * 64 + rf * 16 + quad * 4 + reg;
                const size_t off = (size_t)row * 512 + colg;
                const float ig = acc[rf][cc][0][reg] + bsum[cc][0];
                const float fg = acc[rf][cc][1][reg] + bsum[cc][1];
                const float gg = acc[rf][cc][2][reg] + bsum[cc][2];
                const float og = acc[rf][cc][3][reg] + bsum[cc][3];
                const float cp = __builtin_nontemporal_load(c_prev + off);
                const float cn = sigmoidf_(fg) * cp + sigmoidf_(ig) * tanhf_(gg);
                const float hn = sigmoidf_(og) * tanhf_(cn);
                __builtin_nontemporal_store(hn, h_out + off);
                __builtin_nontemporal_store(cn, c_out + off);
            }
        }
}

// ---- Fallback (round-1 kernel, proven): used only if ws_size < WS_NEEDED ----
#define LDSK 72
__global__ __launch_bounds__(256, 3) void lstm_fused_v1(
    const float* __restrict__ x, const float* __restrict__ h_prev,
    const float* __restrict__ c_prev, const float* __restrict__ w_ih,
    const float* __restrict__ w_hh, const float* __restrict__ b_ih,
    const float* __restrict__ b_hh, float* __restrict__ h_out,
    float* __restrict__ c_out)
{
    __shared__ u16 sA[128][LDSK];
    __shared__ u16 sW[128][LDSK];
    const int t = threadIdx.x;
    const int bn = blockIdx.x & 15, bm = blockIdx.x >> 4;
    const int n0 = bn * 32, rowBase = bm * 128;
    const int srow = t >> 4, scol = t & 15;
    const int lane = t & 63, wv = t >> 6, colin = lane & 15, quad = lane >> 4;
    f32x4 acc[2][2][4];
    #pragma unroll
    for (int rf = 0; rf < 2; ++rf)
        #pragma unroll
        for (int cc = 0; cc < 2; ++cc)
            #pragma unroll
            for (int g = 0; g < 4; ++g) acc[rf][cc][g] = (f32x4){0.f, 0.f, 0.f, 0.f};
    for (int k0 = 0; k0 < KTOT; k0 += 64) {
        const int kk = (k0 < 512) ? k0 : (k0 - 512);
        const float* aSrc = (k0 < 512) ? x : h_prev;
        const float* wSrc = (k0 < 512) ? w_ih : w_hh;
        __syncthreads();
        #pragma unroll
        for (int p = 0; p < 8; ++p) {
            const int r = srow + p * 16;
            const float4 av = *(const float4*)(aSrc + (size_t)(rowBase + r) * 512 + kk + scol * 4);
            ushort4 ap; ap.x = f2bf(av.x); ap.y = f2bf(av.y); ap.z = f2bf(av.z); ap.w = f2bf(av.w);
            *(ushort4*)&sA[r][scol * 4] = ap;
            const int gate = r >> 5, rr = r & 31;
            const float4 wvv = *(const float4*)(wSrc + (size_t)(gate * 512 + n0 + rr) * 512 + kk + scol * 4);
            ushort4 wp; wp.x = f2bf(wvv.x); wp.y = f2bf(wvv.y); wp.z = f2bf(wvv.z); wp.w = f2bf(wvv.w);
            *(ushort4*)&sW[r][scol * 4] = wp;
        }
        __syncthreads();
        #pragma unroll
        for (int ks = 0; ks < 2; ++ks) {
            short8 af[2];
            #pragma unroll
            for (int rf = 0; rf < 2; ++rf)
                af[rf] = *(const short8*)&sA[wv * 32 + rf * 16 + colin][ks * 32 + quad * 8];
            short8 bfr[2][4];
            #pragma unroll
            for (int cc = 0; cc < 2; ++cc)
                #pragma unroll
                for (int g = 0; g < 4; ++g)
                    bfr[cc][g] = *(const short8*)&sW[g * 32 + cc * 16 + colin][ks * 32 + quad * 8];
            #pragma unroll
            for (int rf = 0; rf < 2; ++rf)
                #pragma unroll
                for (int cc = 0; cc < 2; ++cc)
                    #pragma unroll
                    for (int g = 0; g < 4; ++g)
                        acc[rf][cc][g] = __builtin_amdgcn_mfma_f32_16x16x32_bf16(
                            af[rf], bfr[cc][g], acc[rf][cc][g], 0, 0, 0);
        }
    }
    float bsum[2][4];
    #pragma unroll
    for (int cc = 0; cc < 2; ++cc) {
        const int colg = n0 + cc * 16 + colin;
        #pragma unroll
        for (int g = 0; g < 4; ++g) bsum[cc][g] = b_ih[g * 512 + colg] + b_hh[g * 512 + colg];
    }
    #pragma unroll
    for (int rf = 0; rf < 2; ++rf)
        #pragma unroll
        for (int cc = 0; cc < 2; ++cc) {
            const int colg = n0 + cc * 16 + colin;
            #pragma unroll
            for (int reg = 0; reg < 4; ++reg) {
                const int row = rowBase + wv * 32 + rf * 16 + quad * 4 + reg;
                const size_t off = (size_t)row * 512 + colg;
                const float ig = acc[rf][cc][0][reg] + bsum[cc][0];
                const float fg = acc[rf][cc][1][reg] + bsum[cc][1];
                const float gg = acc[rf][cc][2][reg] + bsum[cc][2];
                const float og = acc[rf][cc][3][reg] + bsum[cc][3];
                const float cp = c_prev[off];
                const float cn = sigmoidf_(fg) * cp + sigmoidf_(ig) * tanhf_(gg);
                const float hn = sigmoidf_(og) * tanhf_(cn);
                h_out[off] = hn;
                c_out[off] = cn;
            }
        }
}

extern "C" void kernel_launch(void* const* d_in, const int* in_sizes, int n_in,
                              void* d_out, int out_size, void* d_ws, size_t ws_size,
                              hipStream_t stream) {
    const float* x      = (const float*)d_in[0];
    const float* h_prev = (const float*)d_in[1];
    const float* c_prev = (const float*)d_in[2];
    const float* w_ih   = (const float*)d_in[3];
    const float* w_hh   = (const float*)d_in[4];
    const float* b_ih   = (const float*)d_in[5];
    const float* b_hh   = (const float*)d_in[6];
    float* h_out = (float*)d_out;
    float* c_out = h_out + (size_t)BATCH * HID;

    if (ws_size >= WS_NEEDED) {
        u16* wsA = (u16*)d_ws;
        u16* wsW = (u16*)((char*)d_ws + WSA_BYTES);
        pack_all<<<(A_CHUNKS + W_CHUNKS) / 256, 256, 0, stream>>>(x, h_prev, w_ih, w_hh, wsA, wsW);
        lstm_gemm<<<NBM * NBN, 256, 0, stream>>>(wsA, wsW, c_prev, b_ih, b_hh, h_out, c_out);
    } else {
        lstm_fused_v1<<<128 * 16, 256, 0, stream>>>(x, h_prev, c_prev, w_ih, w_hh, b_ih, b_hh, h_out, c_out);
    }
}

// Round 4
// 214.251 us; speedup vs baseline: 2.0704x; 1.0907x over previous
//
#include <hip/hip_runtime.h>

// INT8 LSTM cell v4: true-int8 GEMM path.
//   gates = A @ W^T + b,  A = [x|h] (16384 x 1024), W = [w_ih|w_hh] (2048 x 1024)
// Key insight: W is EXACTLY int8*scale (reference quant_dequant). max|W| = 127*s_w,
// so q_w = rint(W * 127/max|W|) recovers the int grid losslessly. A is quantized
// per-row (s_b = rowmax/127). GEMM uses mfma_i32_16x16x64_i8 (2xK, ~2x bf16 rate);
// BK=128 int8 keeps the exact same 128B-row swizzled layout/addressing as the
// proven bf16 kernel but halves KSTEPS (16->8): half the barriers/LDS/staging.
// Epilogue: gate = i32acc * (s_b * s_w) + bias -> in-register LSTM math.

typedef __attribute__((ext_vector_type(4))) int int4v;
typedef __attribute__((ext_vector_type(8))) short short8;
typedef __attribute__((ext_vector_type(4))) float f32x4;
typedef unsigned int u32;
typedef unsigned short u16;
typedef unsigned char u8;

#define BATCH 16384
#define HID 512
#define KTOT 1024
#define BM 256
#define KSTEPS 8                  // KTOT / 128
#define TILEA_BYTES 32768         // 256 rows * 128 int8
#define TILEW_BYTES 16384         // 128 rows * 128 int8
#define NBM 64
#define NBN 16
#define WSA_BYTES ((size_t)NBM * KSTEPS * TILEA_BYTES)   // 16 MB
#define WSW_BYTES ((size_t)NBN * KSTEPS * TILEW_BYTES)   // 2 MB
#define SCALE_OFF (WSA_BYTES + WSW_BYTES)                // per-row A scales (64 KB)
#define PART_OFF (SCALE_OFF + 65536)                     // 512 W-max partials
#define SW_OFF (PART_OFF + 2048)                         // W scale scalar
#define WS_NEEDED (SW_OFF + 64)

__device__ __forceinline__ float sigmoidf_(float v) { return 1.0f / (1.0f + __expf(-v)); }
__device__ __forceinline__ float tanhf_(float v) { return 1.0f - 2.0f / (__expf(2.0f * v) + 1.0f); }

__device__ __forceinline__ void gload_lds16(const void* g, void* l) {
    __builtin_amdgcn_global_load_lds(
        (const __attribute__((address_space(1))) u32*)g,
        (__attribute__((address_space(3))) u32*)l, 16, 0, 0);
}

__device__ __forceinline__ u32 pack4(float a, float b, float c, float d, float inv) {
    int q0 = (int)rintf(a * inv), q1 = (int)rintf(b * inv);
    int q2 = (int)rintf(c * inv), q3 = (int)rintf(d * inv);
    return (q0 & 255) | ((q1 & 255) << 8) | ((q2 & 255) << 16) | ((q3 & 255) << 24);
}

// ---- Stage 0: per-block partial max|W| over both weight matrices (512 partials) ----
__global__ __launch_bounds__(256) void wmax_part(
    const float* __restrict__ w_ih, const float* __restrict__ w_hh, float* __restrict__ part)
{
    const u32 b = blockIdx.x;  // 0..511; each block covers 4096 contiguous floats
    const float* src = (b < 256) ? (w_ih + (size_t)b * 4096) : (w_hh + (size_t)(b - 256) * 4096);
    const u32 t = threadIdx.x;
    float am = 0.f;
    const float4* p = (const float4*)src + t;
    #pragma unroll
    for (int j = 0; j < 4; ++j) {
        float4 v = p[j * 256];
        am = fmaxf(am, fmaxf(fmaxf(fabsf(v.x), fabsf(v.y)), fmaxf(fabsf(v.z), fabsf(v.w))));
    }
    #pragma unroll
    for (int o = 32; o >= 1; o >>= 1) am = fmaxf(am, __shfl_xor(am, o, 64));
    __shared__ float red[4];
    if ((t & 63) == 0) red[t >> 6] = am;
    __syncthreads();
    if (t == 0) part[b] = fmaxf(fmaxf(red[0], red[1]), fmaxf(red[2], red[3]));
}

// ---- Stage 1b: pack W -> exact int8 swizzled tiles. One 16B chunk per thread. ----
// Tile chunk layout: linear index = ((bn*8+ks)*128 + row)*8 + cphys, cphys = clog^(row&7).
__global__ __launch_bounds__(256) void pack_w(
    const float* __restrict__ w_ih, const float* __restrict__ w_hh,
    const float* __restrict__ part, u8* __restrict__ wsW, float* __restrict__ swOut)
{
    const u32 t = threadIdx.x;
    // every block redundantly reduces the 512 partials (2 KB, cached) -> wmax
    float am = fmaxf(part[t], part[t + 256]);
    #pragma unroll
    for (int o = 32; o >= 1; o >>= 1) am = fmaxf(am, __shfl_xor(am, o, 64));
    __shared__ float red[4];
    if ((t & 63) == 0) red[t >> 6] = am;
    __syncthreads();
    const float wmax = fmaxf(fmaxf(red[0], red[1]), fmaxf(red[2], red[3]));
    const float inv = 127.0f / wmax;   // exact int recovery: W = q*s_w, wmax = 127*s_w
    if (blockIdx.x == 0 && t == 0) *swOut = wmax * (1.0f / 127.0f);

    const u32 widx = blockIdx.x * 256 + t;      // 131072 chunks
    const u32 cphys = widx & 7;
    const u32 row = (widx >> 3) & 127;          // g*32 + rr
    const u32 ks = (widx >> 10) & 7;
    const u32 bn = widx >> 13;
    const u32 clog = cphys ^ (row & 7);
    const u32 g = row >> 5, rr = row & 31;
    const u32 wrow = g * 512 + bn * 32 + rr;
    const u32 kglob = ks * 128 + clog * 16;
    const float* src = (kglob < 512) ? (w_ih + (size_t)wrow * 512 + kglob)
                                     : (w_hh + (size_t)wrow * 512 + (kglob - 512));
    u32 wds[4];
    #pragma unroll
    for (int j = 0; j < 4; ++j) {
        float4 v = *((const float4*)src + j);
        wds[j] = pack4(v.x, v.y, v.z, v.w, inv);
    }
    int4v val = {(int)wds[0], (int)wds[1], (int)wds[2], (int)wds[3]};
    *(int4v*)(wsW + (size_t)widx * 16) = val;
}

// ---- Stage 1a: pack A with per-row scale; one wave per row (row fits in wave regs). ----
__global__ __launch_bounds__(256) void pack_a(
    const float* __restrict__ x, const float* __restrict__ h_prev,
    u8* __restrict__ wsA, float* __restrict__ aScale)
{
    const u32 t = threadIdx.x;
    const u32 lane = t & 63;
    const u32 m = blockIdx.x * 4 + (t >> 6);
    const u32 k0 = lane * 16;                 // lane covers k [16*lane, 16*lane+16)
    const float* src = (k0 < 512) ? (x + (size_t)m * 512 + k0)
                                  : (h_prev + (size_t)m * 512 + (k0 - 512));
    float4 v[4];
    #pragma unroll
    for (int j = 0; j < 4; ++j) v[j] = *((const float4*)src + j);
    float am = 0.f;
    #pragma unroll
    for (int j = 0; j < 4; ++j)
        am = fmaxf(am, fmaxf(fmaxf(fabsf(v[j].x), fabsf(v[j].y)),
                             fmaxf(fabsf(v[j].z), fabsf(v[j].w))));
    #pragma unroll
    for (int o = 32; o >= 1; o >>= 1) am = fmaxf(am, __shfl_xor(am, o, 64));
    const float inv = (am > 0.f) ? 127.0f / am : 0.f;
    if (lane == 0) aScale[m] = am * (1.0f / 127.0f);
    u32 wds[4];
    #pragma unroll
    for (int j = 0; j < 4; ++j) wds[j] = pack4(v[j].x, v[j].y, v[j].z, v[j].w, inv);
    const u32 bm = m >> 8, row = m & 255;
    const u32 ks = lane >> 3, clog = lane & 7;
    const u32 cphys = clog ^ (row & 7);
    int4v val = {(int)wds[0], (int)wds[1], (int)wds[2], (int)wds[3]};
    *(int4v*)(wsA + ((((size_t)bm * 8 + ks) * 256 + row) * 8 + cphys) * 16) = val;
}

// ---- Stage 2: i8 GEMM + fused LSTM epilogue. BM=256, 4 waves x 64 rows. ----
__global__ __launch_bounds__(256, 2) void lstm_gemm(
    const u8* __restrict__ wsA, const u8* __restrict__ wsW,
    const float* __restrict__ aScale, const float* __restrict__ swPtr,
    const float* __restrict__ c_prev,
    const float* __restrict__ b_ih, const float* __restrict__ b_hh,
    float* __restrict__ h_out, float* __restrict__ c_out)
{
    __shared__ u8 sA[TILEA_BYTES];  // 32 KB, swizzled, NO padding (global_load_lds)
    __shared__ u8 sW[TILEW_BYTES];  // 16 KB

    const int t = threadIdx.x;
    const int bn = blockIdx.x & 15;
    const int bm = blockIdx.x >> 4;
    const int n0 = bn * 32;
    const int rowBase = bm * BM;

    const int lane = t & 63;
    const int wv = t >> 6;
    const int colin = lane & 15;
    const int quad = lane >> 4;
    const int stageOff = t * 16;

    int4v acc[4][2][4];  // [row-frag][col-frag][gate]
    #pragma unroll
    for (int rf = 0; rf < 4; ++rf)
        #pragma unroll
        for (int cc = 0; cc < 2; ++cc)
            #pragma unroll
            for (int g = 0; g < 4; ++g)
                acc[rf][cc][g] = (int4v){0, 0, 0, 0};

    const char* gA = (const char*)wsA + (size_t)bm * KSTEPS * TILEA_BYTES;
    const char* gW = (const char*)wsW + (size_t)bn * KSTEPS * TILEW_BYTES;

    #pragma unroll 1
    for (int ks = 0; ks < KSTEPS; ++ks) {
        __syncthreads();
        #pragma unroll
        for (int j = 0; j < 8; ++j)
            gload_lds16(gA + (size_t)ks * TILEA_BYTES + j * 4096 + stageOff,
                        (char*)sA + j * 4096 + stageOff);
        #pragma unroll
        for (int j = 0; j < 4; ++j)
            gload_lds16(gW + (size_t)ks * TILEW_BYTES + j * 4096 + stageOff,
                        (char*)sW + j * 4096 + stageOff);
        __syncthreads();

        #pragma unroll
        for (int ks2 = 0; ks2 < 2; ++ks2) {  // K=64 per MFMA, chunk = ks2*4+quad
            int4v af[4];
            #pragma unroll
            for (int rf = 0; rf < 4; ++rf) {
                const int row = wv * 64 + rf * 16 + colin;
                const int boff = row * 128 + (((ks2 * 4 + quad) ^ (row & 7)) * 16);
                af[rf] = *(const int4v*)((const char*)sA + boff);
            }
            int4v bfr[2][4];
            #pragma unroll
            for (int cc = 0; cc < 2; ++cc)
                #pragma unroll
                for (int g = 0; g < 4; ++g) {
                    const int wrow = g * 32 + cc * 16 + colin;
                    const int boff = wrow * 128 + (((ks2 * 4 + quad) ^ (wrow & 7)) * 16);
                    bfr[cc][g] = *(const int4v*)((const char*)sW + boff);
                }
            #pragma unroll
            for (int rf = 0; rf < 4; ++rf)
                #pragma unroll
                for (int cc = 0; cc < 2; ++cc)
                    #pragma unroll
                    for (int g = 0; g < 4; ++g)
                        acc[rf][cc][g] = __builtin_amdgcn_mfma_i32_16x16x64_i8(
                            af[rf], bfr[cc][g], acc[rf][cc][g], 0, 0, 0);
        }
    }

    // Epilogue: dequant (per-row scale * W scale), bias, LSTM math — all in-lane.
    const float sw = *swPtr;
    float rsc[4][4];
    #pragma unroll
    for (int rf = 0; rf < 4; ++rf)
        #pragma unroll
        for (int reg = 0; reg < 4; ++reg)
            rsc[rf][reg] = aScale[rowBase + wv * 64 + rf * 16 + quad * 4 + reg] * sw;

    float bsum[2][4];
    #pragma unroll
    for (int cc = 0; cc < 2; ++cc) {
        const int colg = n0 + cc * 16 + colin;
        #pragma unroll
        for (int g = 0; g < 4; ++g)
            bsum[cc][g] = b_ih[g * 512 + colg] + b_hh[g * 512 + colg];
    }

    #pragma unroll
    for (int rf = 0; rf < 4; ++rf)
        #pragma unroll
        for (int cc = 0; cc < 2; ++cc) {
            const int colg = n0 + cc * 16 + colin;
            #pragma unroll
            for (int reg = 0; reg < 4; ++reg) {
                const int row = rowBase + wv * 64 + rf * 16 + quad * 4 + reg;
                const size_t off = (size_t)row * 512 + colg;
                const float s = rsc[rf][reg];
                const float ig = (float)acc[rf][cc][0][reg] * s + bsum[cc][0];
                const float fg = (float)acc[rf][cc][1][reg] * s + bsum[cc][1];
                const float gg = (float)acc[rf][cc][2][reg] * s + bsum[cc][2];
                const float og = (float)acc[rf][cc][3][reg] * s + bsum[cc][3];
                const float cp = __builtin_nontemporal_load(c_prev + off);
                const float cn = sigmoidf_(fg) * cp + sigmoidf_(ig) * tanhf_(gg);
                const float hn = sigmoidf_(og) * tanhf_(cn);
                __builtin_nontemporal_store(hn, h_out + off);
                __builtin_nontemporal_store(cn, c_out + off);
            }
        }
}

// ---- Fallback (round-1 kernel, proven): used only if ws_size < WS_NEEDED ----
#define LDSK 72
__device__ __forceinline__ u16 f2bf(float f) {
    u32 u = __builtin_bit_cast(u32, f);
    u += 0x7FFFu + ((u >> 16) & 1u);
    return (u16)(u >> 16);
}
__global__ __launch_bounds__(256, 3) void lstm_fused_v1(
    const float* __restrict__ x, const float* __restrict__ h_prev,
    const float* __restrict__ c_prev, const float* __restrict__ w_ih,
    const float* __restrict__ w_hh, const float* __restrict__ b_ih,
    const float* __restrict__ b_hh, float* __restrict__ h_out,
    float* __restrict__ c_out)
{
    __shared__ u16 sA[128][LDSK];
    __shared__ u16 sW[128][LDSK];
    const int t = threadIdx.x;
    const int bn = blockIdx.x & 15, bm = blockIdx.x >> 4;
    const int n0 = bn * 32, rowBase = bm * 128;
    const int srow = t >> 4, scol = t & 15;
    const int lane = t & 63, wv = t >> 6, colin = lane & 15, quad = lane >> 4;
    f32x4 acc[2][2][4];
    #pragma unroll
    for (int rf = 0; rf < 2; ++rf)
        #pragma unroll
        for (int cc = 0; cc < 2; ++cc)
            #pragma unroll
            for (int g = 0; g < 4; ++g) acc[rf][cc][g] = (f32x4){0.f, 0.f, 0.f, 0.f};
    for (int k0 = 0; k0 < KTOT; k0 += 64) {
        const int kk = (k0 < 512) ? k0 : (k0 - 512);
        const float* aSrc = (k0 < 512) ? x : h_prev;
        const float* wSrc = (k0 < 512) ? w_ih : w_hh;
        __syncthreads();
        #pragma unroll
        for (int p = 0; p < 8; ++p) {
            const int r = srow + p * 16;
            const float4 av = *(const float4*)(aSrc + (size_t)(rowBase + r) * 512 + kk + scol * 4);
            ushort4 ap; ap.x = f2bf(av.x); ap.y = f2bf(av.y); ap.z = f2bf(av.z); ap.w = f2bf(av.w);
            *(ushort4*)&sA[r][scol * 4] = ap;
            const int gate = r >> 5, rr = r & 31;
            const float4 wvv = *(const float4*)(wSrc + (size_t)(gate * 512 + n0 + rr) * 512 + kk + scol * 4);
            ushort4 wp; wp.x = f2bf(wvv.x); wp.y = f2bf(wvv.y); wp.z = f2bf(wvv.z); wp.w = f2bf(wvv.w);
            *(ushort4*)&sW[r][scol * 4] = wp;
        }
        __syncthreads();
        #pragma unroll
        for (int ks = 0; ks < 2; ++ks) {
            short8 af[2];
            #pragma unroll
            for (int rf = 0; rf < 2; ++rf)
                af[rf] = *(const short8*)&sA[wv * 32 + rf * 16 + colin][ks * 32 + quad * 8];
            short8 bfr[2][4];
            #pragma unroll
            for (int cc = 0; cc < 2; ++cc)
                #pragma unroll
                for (int g = 0; g < 4; ++g)
                    bfr[cc][g] = *(const short8*)&sW[g * 32 + cc * 16 + colin][ks * 32 + quad * 8];
            #pragma unroll
            for (int rf = 0; rf < 2; ++rf)
                #pragma unroll
                for (int cc = 0; cc < 2; ++cc)
                    #pragma unroll
                    for (int g = 0; g < 4; ++g)
                        acc[rf][cc][g] = __builtin_amdgcn_mfma_f32_16x16x32_bf16(
                            af[rf], bfr[cc][g], acc[rf][cc][g], 0, 0, 0);
        }
    }
    float bsum[2][4];
    #pragma unroll
    for (int cc = 0; cc < 2; ++cc) {
        const int colg = n0 + cc * 16 + colin;
        #pragma unroll
        for (int g = 0; g < 4; ++g) bsum[cc][g] = b_ih[g * 512 + colg] + b_hh[g * 512 + colg];
    }
    #pragma unroll
    for (int rf = 0; rf < 2; ++rf)
        #pragma unroll
        for (int cc = 0; cc < 2; ++cc) {
            const int colg = n0 + cc * 16 + colin;
            #pragma unroll
            for (int reg = 0; reg < 4; ++reg) {
                const int row = rowBase + wv * 32 + rf * 16 + quad * 4 + reg;
                const size_t off = (size_t)row * 512 + colg;
                const float ig = acc[rf][cc][0][reg] + bsum[cc][0];
                const float fg = acc[rf][cc][1][reg] + bsum[cc][1];
                const float gg = acc[rf][cc][2][reg] + bsum[cc][2];
                const float og = acc[rf][cc][3][reg] + bsum[cc][3];
                const float cp = c_prev[off];
                const float cn = sigmoidf_(fg) * cp + sigmoidf_(ig) * tanhf_(gg);
                const float hn = sigmoidf_(og) * tanhf_(cn);
                h_out[off] = hn;
                c_out[off] = cn;
            }
        }
}

extern "C" void kernel_launch(void* const* d_in, const int* in_sizes, int n_in,
                              void* d_out, int out_size, void* d_ws, size_t ws_size,
                              hipStream_t stream) {
    const float* x      = (const float*)d_in[0];
    const float* h_prev = (const float*)d_in[1];
    const float* c_prev = (const float*)d_in[2];
    const float* w_ih   = (const float*)d_in[3];
    const float* w_hh   = (const float*)d_in[4];
    const float* b_ih   = (const float*)d_in[5];
    const float* b_hh   = (const float*)d_in[6];
    float* h_out = (float*)d_out;
    float* c_out = h_out + (size_t)BATCH * HID;

    if (ws_size >= WS_NEEDED) {
        u8* wsA = (u8*)d_ws;
        u8* wsW = (u8*)d_ws + WSA_BYTES;
        float* aScale = (float*)((char*)d_ws + SCALE_OFF);
        float* part   = (float*)((char*)d_ws + PART_OFF);
        float* swOut  = (float*)((char*)d_ws + SW_OFF);
        wmax_part<<<512, 256, 0, stream>>>(w_ih, w_hh, part);
        pack_w<<<512, 256, 0, stream>>>(w_ih, w_hh, part, wsW, swOut);
        pack_a<<<BATCH / 4, 256, 0, stream>>>(x, h_prev, wsA, aScale);
        lstm_gemm<<<NBM * NBN, 256, 0, stream>>>(wsA, wsW, aScale, swOut, c_prev,
                                                 b_ih, b_hh, h_out, c_out);
    } else {
        lstm_fused_v1<<<128 * 16, 256, 0, stream>>>(x, h_prev, c_prev, w_ih, w_hh,
                                                    b_ih, b_hh, h_out, c_out);
    }
}